// Round 3
// baseline (531.072 us; speedup 1.0000x reference)
//
#include <hip/hip_runtime.h>
#include <math.h>

typedef __attribute__((ext_vector_type(8))) short short8;
typedef __attribute__((ext_vector_type(4))) float floatx4;

__device__ inline unsigned f2bf1(float f) {
    union { float f; unsigned u; } v; v.f = f;
    return (v.u + 0x8000u) >> 16;   // round-half-up to bf16
}

__device__ inline short8 pack8(float4 a, float4 b) {
    short8 r;
    r[0] = (short)f2bf1(a.x); r[1] = (short)f2bf1(a.y);
    r[2] = (short)f2bf1(a.z); r[3] = (short)f2bf1(a.w);
    r[4] = (short)f2bf1(b.x); r[5] = (short)f2bf1(b.y);
    r[6] = (short)f2bf1(b.z); r[7] = (short)f2bf1(b.w);
    return r;
}

__device__ inline float gelu1(float x) {
    return 0.5f * x * (1.0f + erff(x * 0.70710678118654752f));
}

__device__ inline float4 lnmap(float4 v, float m, float rs, float4 g, float4 b, int addres) {
    float4 o;
    o.x = (v.x - m) * rs * g.x + b.x;
    o.y = (v.y - m) * rs * g.y + b.y;
    o.z = (v.z - m) * rs * g.z + b.z;
    o.w = (v.w - m) * rs * g.w + b.w;
    if (addres) { o.x += v.x; o.y += v.y; o.z += v.z; o.w += v.w; }
    return o;
}

__device__ inline float4 gelmap(float4 v, float4 b) {
    float4 o;
    o.x = gelu1(v.x + b.x);
    o.y = gelu1(v.y + b.y);
    o.z = gelu1(v.z + b.z);
    o.w = gelu1(v.w + b.w);
    return o;
}

// -------- segment-average: x (16,128,512) -> xcf (32, 2048), m = b*16 + a ----
__global__ __launch_bounds__(128) void avg_k(const float* __restrict__ x,
                                             float* __restrict__ xcf) {
    int blk = blockIdx.x;            // a*128 + b
    int a = blk >> 7, b = blk & 127;
    int t = threadIdx.x;
    const float4 v = *(const float4*)(x + ((size_t)a * 128 + b) * 512 + t * 4);
    float s = v.x + v.y + v.z + v.w;
    s += __shfl_xor(s, 1);
    s += __shfl_xor(s, 2);
    if ((t & 3) == 0) {
        int seg = t >> 2;            // 0..31
        xcf[seg * 2048 + b * 16 + a] = s * (1.0f / 16.0f);
    }
}

// -------- LN stats only: per row of 2048, write {mean, rstd} (two-pass) ------
__global__ __launch_bounds__(256) void stats_k(const float* __restrict__ Sin,
                                               float* __restrict__ st) {
    __shared__ float red[8];
    const int row = blockIdx.x, t = threadIdx.x;
    const float* xr = Sin + (size_t)row * 2048;
    float4 v0 = *(const float4*)(xr + t * 4);
    float4 v1 = *(const float4*)(xr + 1024 + t * 4);
    float s = v0.x + v0.y + v0.z + v0.w + v1.x + v1.y + v1.z + v1.w;
    for (int o = 32; o; o >>= 1) s += __shfl_down(s, o);
    if ((t & 63) == 0) red[t >> 6] = s;
    __syncthreads();
    float mean = (red[0] + red[1] + red[2] + red[3]) * (1.0f / 2048.0f);
    float d0 = v0.x - mean, d1 = v0.y - mean, d2 = v0.z - mean, d3 = v0.w - mean;
    float e0 = v1.x - mean, e1 = v1.y - mean, e2 = v1.z - mean, e3 = v1.w - mean;
    float s2 = d0*d0 + d1*d1 + d2*d2 + d3*d3 + e0*e0 + e1*e1 + e2*e2 + e3*e3;
    for (int o = 32; o; o >>= 1) s2 += __shfl_down(s2, o);
    if ((t & 63) == 0) red[4 + (t >> 6)] = s2;
    __syncthreads();
    if (t == 0) {
        float var = (red[4] + red[5] + red[6] + red[7]) * (1.0f / 2048.0f);
        st[row * 2]     = mean;
        st[row * 2 + 1] = 1.0f / sqrtf(var + 1e-5f);
    }
}

// -------- S += cumsum_rows(U): uses matmul linearity, cumsum(V)@Wo^T == cumsum(V@Wo^T)
__global__ __launch_bounds__(256) void cumadd_k(const float* __restrict__ U,
                                                float* __restrict__ S) {
    int c = blockIdx.x * 256 + threadIdx.x;   // 8 blocks x 256 = 2048 cols
    float run = 0.f;
#pragma unroll
    for (int r = 0; r < 32; r++) {
        run += U[r * 2048 + c];
        S[r * 2048 + c] += run;
    }
}

// -------- streaming thin GEMM: C[32,N] (+)= f(X)[32,K] @ W[N,K]^T ------------
// 16-wave blocks; block owns 16 output cols; waves split K (KPW each) with an
// LDS reduction at block end -> ONE store per output (ATOM only when gridDim.y>1).
// No LDS staging, no barriers in the stream loop: A-fragments read straight
// from global (X is L2-resident; identical (row,k)->lane mapping as before).
// STAGE: 0 plain; 1 LN(stats,sg,sb); 11 LN+residual; 3 gelu(X + sg[k])
// EPI:   0 plain; 1 +ebias[n] (by==0); 2 +sinusoidal posbias (by==0)
template<int KPW, int STAGE, int EPI, int ATOM>
__global__ __launch_bounds__(1024, 4) void gemm_k(const float* __restrict__ X,
                                                  const float* __restrict__ W,
                                                  float* __restrict__ C,
                                                  const float* __restrict__ ebias,
                                                  const float* __restrict__ stats,
                                                  const float* __restrict__ sg,
                                                  const float* __restrict__ sb,
                                                  int N, int K) {
    __shared__ float red[16 * 512];          // 32 KB: per-wave partial C tiles
    const int tid = threadIdx.x;
    const int w = tid >> 6, lane = tid & 63;
    const int q = lane >> 4, r16 = lane & 15;
    const int nb = blockIdx.x * 16;                          // output cols
    const int kb0 = (blockIdx.y * 16 + w) * KPW;             // this wave's K-slice

    const float* wp  = W + (size_t)(nb + r16) * K + kb0 + q * 8;
    const float* xp0 = X + (size_t)r16 * K + kb0 + q * 8;
    const float* xp1 = X + (size_t)(16 + r16) * K + kb0 + q * 8;

    float m0 = 0.f, rs0 = 0.f, m1 = 0.f, rs1 = 0.f;
    if constexpr (STAGE == 1 || STAGE == 11) {
        m0 = stats[r16 * 2];        rs0 = stats[r16 * 2 + 1];
        m1 = stats[(16 + r16) * 2]; rs1 = stats[(16 + r16) * 2 + 1];
    }

    floatx4 acc0 = {}, acc1 = {};
#pragma unroll
    for (int ks = 0; ks < KPW; ks += 32) {
        const int k0 = kb0 + ks + q * 8;
        float4 w0  = *(const float4*)(wp + ks);
        float4 w1  = *(const float4*)(wp + ks + 4);
        float4 x00 = *(const float4*)(xp0 + ks);
        float4 x01 = *(const float4*)(xp0 + ks + 4);
        float4 x10 = *(const float4*)(xp1 + ks);
        float4 x11 = *(const float4*)(xp1 + ks + 4);
        if constexpr (STAGE == 1 || STAGE == 11) {
            const float4 g0 = *(const float4*)(sg + k0);
            const float4 g1 = *(const float4*)(sg + k0 + 4);
            const float4 b0 = *(const float4*)(sb + k0);
            const float4 b1 = *(const float4*)(sb + k0 + 4);
            const int ar = (STAGE == 11);
            x00 = lnmap(x00, m0, rs0, g0, b0, ar);
            x01 = lnmap(x01, m0, rs0, g1, b1, ar);
            x10 = lnmap(x10, m1, rs1, g0, b0, ar);
            x11 = lnmap(x11, m1, rs1, g1, b1, ar);
        }
        if constexpr (STAGE == 3) {
            const float4 c0 = *(const float4*)(sg + k0);
            const float4 c1 = *(const float4*)(sg + k0 + 4);
            x00 = gelmap(x00, c0);
            x01 = gelmap(x01, c1);
            x10 = gelmap(x10, c0);
            x11 = gelmap(x11, c1);
        }
        short8 bw = pack8(w0, w1);
        short8 a0 = pack8(x00, x01);
        short8 a1 = pack8(x10, x11);
        acc0 = __builtin_amdgcn_mfma_f32_16x16x32_bf16(a0, bw, acc0, 0, 0, 0);
        acc1 = __builtin_amdgcn_mfma_f32_16x16x32_bf16(a1, bw, acc1, 0, 0, 0);
    }

    // ---- block reduction over the 16 waves' K-partials ----
    {
        const int base = w * 512 + q * 64 + r16;   // i = mt*16 + q*4 + e, c = r16
#pragma unroll
        for (int e = 0; e < 4; e++) {
            red[base + e * 16]       = acc0[e];
            red[base + 256 + e * 16] = acc1[e];
        }
    }
    __syncthreads();
    if (tid < 512) {
        float v = 0.f;
#pragma unroll
        for (int ww = 0; ww < 16; ww++) v += red[ww * 512 + tid];
        const int i = tid >> 4;              // output row 0..31
        const int n = nb + (tid & 15);       // output col
        if (EPI == 1 && blockIdx.y == 0) v += ebias[n];
        if (EPI == 2 && blockIdx.y == 0) {
            int ne = n & ~1;
            float ang = (float)i * __expf(-(float)ne * (9.210340371976184f / 1024.0f));
            v += (n & 1) ? cosf(ang) : sinf(ang);
        }
        if constexpr (ATOM) atomicAdd(C + (size_t)i * N + n, v);
        else                C[(size_t)i * N + n] = v;
    }
}

extern "C" void kernel_launch(void* const* d_in, const int* in_sizes, int n_in,
                              void* d_out, int out_size, void* d_ws, size_t ws_size,
                              hipStream_t stream) {
    const float* x      = (const float*)d_in[0];
    const float* weight = (const float*)d_in[1];
    // d_in[2] = Wq, d_in[3] = Wk: dead (softmax over a scalar == 1)
    const float* Wv     = (const float*)d_in[4];
    const float* Wo     = (const float*)d_in[5];
    const float* ln1g   = (const float*)d_in[6];
    const float* ln1b   = (const float*)d_in[7];
    const float* ln2g   = (const float*)d_in[8];
    const float* ln2b   = (const float*)d_in[9];
    const float* fc1w   = (const float*)d_in[10];
    const float* fc1b   = (const float*)d_in[11];
    const float* fc2w   = (const float*)d_in[12];
    const float* fc2b   = (const float*)d_in[13];
    float* ws  = (float*)d_ws;
    float* xcf = ws;                 // 32*2048
    float* S   = ws + 65536;         // 32*2048
    float* V   = ws + 131072;        // 32*2048   (V,U adjacent: one memset)
    float* U   = ws + 196608;        // 32*2048
    float* H   = ws + 262144;        // 32*8192
    float* st1 = ws + 524288;        // 32*2  {mean, rstd}
    float* st2 = ws + 524352;        // 32*2
    float* out = (float*)d_out;

    avg_k<<<2048, 128, 0, stream>>>(x, xcf);

    // S = xcf @ weight^T + posbias   (2 K-segments -> 2 atomic partials/out)
    hipMemsetAsync(S, 0, 65536 * 4, stream);
    gemm_k<64, 0, 2, 1><<<dim3(128, 2), 1024, 0, stream>>>(
        xcf, weight, S, nullptr, nullptr, nullptr, nullptr, 2048, 2048);

    for (int a = 0; a < 3; a++) {
        // V = LN1(S) @ Wv[a]^T
        stats_k<<<32, 256, 0, stream>>>(S, st1);
        hipMemsetAsync(V, 0, 131072 * 4, stream);          // zeros V and U
        gemm_k<64, 1, 0, 1><<<dim3(128, 2), 1024, 0, stream>>>(
            S, Wv + (size_t)a * 4194304, V, nullptr, st1, ln1g, ln1b, 2048, 2048);
        // U = V @ Wo[a]^T ; S += cumsum_rows(U)   (cumsum commutes with matmul)
        gemm_k<64, 0, 0, 1><<<dim3(128, 2), 1024, 0, stream>>>(
            V, Wo + (size_t)a * 4194304, U, nullptr, nullptr, nullptr, nullptr, 2048, 2048);
        cumadd_k<<<8, 256, 0, stream>>>(U, S);
        // H = (LN2(S)+S) @ fc1^T   (no split-K: plain stores, no memset)
        stats_k<<<32, 256, 0, stream>>>(S, st2);
        gemm_k<128, 11, 0, 0><<<dim3(512, 1), 1024, 0, stream>>>(
            S, fc1w, H, nullptr, st2, ln2g, ln2b, 8192, 2048);
        // S/out = gelu(H + fc1_b) @ fc2^T + fc2_b
        float* Co = (a == 2) ? out : S;
        hipMemsetAsync(Co, 0, 65536 * 4, stream);
        gemm_k<256, 3, 1, 1><<<dim3(128, 2), 1024, 0, stream>>>(
            H, fc2w, Co, fc2b, nullptr, fc1b, nullptr, 2048, 8192);
    }
}